// Round 1
// baseline (777.204 us; speedup 1.0000x reference)
//
#include <hip/hip_runtime.h>
#include <hip/hip_bf16.h>
#include <math.h>

// HNNLayer fused kernel for MI355X (gfx950).
// Pipeline per row (C=1): t = acosh(h0)*y/||y||; tn = layernorm(t)*gamma+beta;
// v = tn @ W[1:,1:]^T (bf16 MFMA); then hyperbolic bias-transport epilogue.
// expmap0/logmap0 round trips are exact identities and are elided.

#define MINV 1e-15f
#define PROJ_EPSV 0.004f

typedef __bf16 bf16x8 __attribute__((ext_vector_type(8)));
typedef __bf16 bf16x4 __attribute__((ext_vector_type(4)));
typedef float floatx4 __attribute__((ext_vector_type(4)));

// ---------------- prep: W[1:,1:] -> bf16 [256x256] (row j = out col, k inner), bias scalars ----
__global__ __launch_bounds__(256) void prep_kernel(const float* __restrict__ W,
                                                   const float* __restrict__ bias,
                                                   __bf16* __restrict__ Wb,
                                                   float* __restrict__ scal) {
  int b = blockIdx.x;
  if (b < 64) {
    int idx = b * 1024 + threadIdx.x * 4;   // element index into 256x256 Wb
    int j = idx >> 8;                        // Wb row (maps to W row j+1)
    float4 w;
    if (j < 255) w = *(const float4*)(W + idx + 256);  // W[(j+1)*256 + k]
    else w = make_float4(0.f, 0.f, 0.f, 0.f);          // pad row 255 with zeros
    bf16x4 o;
    o[0] = (__bf16)w.x; o[1] = (__bf16)w.y; o[2] = (__bf16)w.z; o[3] = (__bf16)w.w;
    *(bf16x4*)(Wb + idx) = o;
  } else if (threadIdx.x < 64) {
    // sum of bias[1..255]^2 with one wave
    int l = threadIdx.x;
    float4 bv = *(const float4*)(bias + l * 4);
    float s = bv.x * bv.x + bv.y * bv.y + bv.z * bv.z + bv.w * bv.w;
    if (l == 0) s -= bv.x * bv.x;   // exclude bias[0]
    for (int m = 1; m < 64; m <<= 1) s += __shfl_xor(s, m);
    if (l == 0) {
      float nb = sqrtf(s);
      float normu = fminf(nb, 1000.0f);     // MAX_NORM clamp
      float th = fmaxf(normu, MINV);        // theta clip
      scal[0] = coshf(th);                  // c1
      scal[1] = sinhf(th) / th;             // s1 = sinh(th)/th
      scal[2] = s;                          // raw ||b1||^2
    }
  }
}

// ---------------- main fused kernel: 64 rows/block, 16 rows/wave ----------------
__global__ __launch_bounds__(256) void hnn_kernel(const float* __restrict__ h,
                                                  const __bf16* __restrict__ Wb,
                                                  const float* __restrict__ bias,
                                                  const float* __restrict__ gamma,
                                                  const float* __restrict__ beta,
                                                  const float* __restrict__ scal,
                                                  float* __restrict__ out) {
  __shared__ __bf16 Xs[64][264];   // +8 bf16 pad -> A-frag ds_read_b128 conflict-free

  const int tid = threadIdx.x;
  const int wave = tid >> 6;
  const int lane = tid & 63;
  const int rowBlock = blockIdx.x * 64;

  // Hoist gamma/beta for this lane's 4 columns (cols c = lane*4 + i; col 0 -> 0)
  float g[4], be[4];
#pragma unroll
  for (int i = 0; i < 4; ++i) {
    int c = lane * 4 + i;
    g[i]  = (c > 0) ? gamma[c - 1] : 0.f;
    be[i] = (c > 0) ? beta[c - 1]  : 0.f;
  }

  // ---------- Phase A: logmap0 + layernorm -> Xs (bf16) ----------
  for (int rr = 0; rr < 16; ++rr) {
    int lrow = wave * 16 + rr;
    int row = rowBlock + lrow;
    float4 hv = *(const float4*)(h + row * 256 + lane * 4);
    float vals[4] = {hv.x, hv.y, hv.z, hv.w};
    float s1l = vals[0] + vals[1] + vals[2] + vals[3];
    float s2l = vals[0]*vals[0] + vals[1]*vals[1] + vals[2]*vals[2] + vals[3]*vals[3];
    if (lane == 0) { s1l -= vals[0]; s2l -= vals[0]*vals[0]; }  // exclude h0
    for (int m = 1; m < 64; m <<= 1) {
      s1l += __shfl_xor(s1l, m);
      s2l += __shfl_xor(s2l, m);
    }
    float h0 = __shfl(hv.x, 0);
    float yn = fmaxf(sqrtf(s2l), MINV);
    float xc = fmaxf(h0, 1.0f + 1e-7f);
    float theta = acoshf(xc);
    float s = theta / yn;                       // t[k] = s*y[k]
    float mu = s * s1l * (1.0f / 255.0f);
    float var = s * s * (s2l * (1.0f / 255.0f)) - mu * mu;
    float rstd = rsqrtf(var + 1e-5f);
    float a = s * rstd;
    float bshift = -mu * rstd;                  // tn = (a*y + bshift)*gamma + beta
    bf16x4 o;
#pragma unroll
    for (int i = 0; i < 4; ++i) {
      float tn = (a * vals[i] + bshift) * g[i] + be[i];
      o[i] = (__bf16)tn;
    }
    *(bf16x4*)(&Xs[lrow][lane * 4]) = o;
  }
  __syncthreads();

  // ---------- Phase B: GEMM v = tn @ Wb^T, 16 rows x 256 cols per wave ----------
  floatx4 acc[16];
#pragma unroll
  for (int jt = 0; jt < 16; ++jt) acc[jt] = (floatx4){0.f, 0.f, 0.f, 0.f};

  const int m16 = lane & 15;
  const int quad = lane >> 4;
  const __bf16* wbase = Wb + m16 * 256 + quad * 8;          // B frag: n=m16, k=quad*8+i
  const __bf16* xrow = &Xs[wave * 16 + m16][quad * 8];      // A frag: m=m16, k=quad*8+i

#pragma unroll
  for (int kk = 0; kk < 8; ++kk) {
    bf16x8 afr = *(const bf16x8*)(xrow + kk * 32);
#pragma unroll
    for (int jt = 0; jt < 16; ++jt) {
      bf16x8 bfr = *(const bf16x8*)(wbase + jt * 4096 + kk * 32);
      acc[jt] = __builtin_amdgcn_mfma_f32_16x16x32_bf16(afr, bfr, acc[jt], 0, 0, 0);
    }
  }

  // ---------- Phase C: hyperbolic epilogue ----------
  const float c1 = scal[0];
  const float s1s = scal[1];
  const float tb2 = scal[2];

  float bb1[16];
#pragma unroll
  for (int jt = 0; jt < 16; ++jt) {
    int j = jt * 16 + m16;
    bb1[jt] = (j < 255) ? bias[j + 1] : 0.f;
  }

#pragma unroll
  for (int e = 0; e < 4; ++e) {
    int row = rowBlock + wave * 16 + quad * 4 + e;
    float sv2 = 0.f, svb = 0.f;
#pragma unroll
    for (int jt = 0; jt < 16; ++jt) {
      float v = acc[jt][e];
      sv2 += v * v;
      svb += v * bb1[jt];
    }
    for (int m = 1; m < 16; m <<= 1) {
      sv2 += __shfl_xor(sv2, m);
      svb += __shfl_xor(svb, m);
    }
    float n = fmaxf(sqrtf(sv2), MINV);
    float inv_n = 1.0f / n;
    float alpha = svb * inv_n;                       // <vhat, b1>
    float ch = coshf(n), sh = sinhf(n);
    float beta_ = c1 * sh + s1s * alpha * (ch - 1.0f);
    float rn2 = beta_ * beta_ + 2.0f * beta_ * s1s * alpha + s1s * s1s * tb2;
    float res0 = sqrtf(fmaxf(1.0f + rn2, PROJ_EPSV));
    float th3 = acoshf(fmaxf(res0, 1.0f + 1e-7f));
    float rn = fmaxf(sqrtf(rn2), MINV);
    float sc3 = th3 / rn;
    float cvn = beta_ * inv_n;

    float xtv[16];
    float sx2 = 0.f;
#pragma unroll
    for (int jt = 0; jt < 16; ++jt) {
      float r1 = cvn * acc[jt][e] + s1s * bb1[jt];   // res1[j]
      float x = fmaxf(sc3 * r1, 0.f);                // relu(logmap0)
      xtv[jt] = x;
      sx2 += x * x;
    }
    for (int m = 1; m < 16; m <<= 1) sx2 += __shfl_xor(sx2, m);
    float n2 = fmaxf(sqrtf(sx2), MINV);
    float scl = sinhf(n2) / n2;

    float* orow = out + row * 256;
#pragma unroll
    for (int jt = 0; jt < 16; ++jt) {
      int j = jt * 16 + m16;
      if (j < 255) orow[j + 1] = scl * xtv[jt];
    }
    if (m16 == 0) orow[0] = coshf(n2);
  }
}

extern "C" void kernel_launch(void* const* d_in, const int* in_sizes, int n_in,
                              void* d_out, int out_size, void* d_ws, size_t ws_size,
                              hipStream_t stream) {
  const float* h     = (const float*)d_in[0];
  const float* W     = (const float*)d_in[1];
  const float* bias  = (const float*)d_in[2];
  const float* gamma = (const float*)d_in[3];
  const float* beta  = (const float*)d_in[4];
  float* out = (float*)d_out;

  __bf16* Wb  = (__bf16*)d_ws;                      // 256*256*2 = 128 KiB
  float* scal = (float*)((char*)d_ws + 131072);     // 3 floats

  prep_kernel<<<dim3(65), dim3(256), 0, stream>>>(W, bias, Wb, scal);
  hnn_kernel<<<dim3(4096), dim3(256), 0, stream>>>(h, Wb, bias, gamma, beta, scal, out);
}

// Round 2
// 665.940 us; speedup vs baseline: 1.1671x; 1.1671x over previous
//
#include <hip/hip_runtime.h>
#include <hip/hip_bf16.h>
#include <math.h>

// HNNLayer fused kernel for MI355X (gfx950).
// Per row (C=1): t = acosh(h0)*y/||y||; tn = layernorm(t)*gamma+beta;
// v = tn @ W[1:,1:]^T (bf16 MFMA); hyperbolic bias-transport epilogue.
// expmap0/logmap0 round trips are exact identities and are elided.

#define MINV 1e-15f

typedef __bf16 bf16x8 __attribute__((ext_vector_type(8)));
typedef __bf16 bf16x4 __attribute__((ext_vector_type(4)));
typedef float floatx4 __attribute__((ext_vector_type(4)));

// ---- prep: W[1:,1:] -> bf16 [256x256] (row j = out col), bias scalars ----
__global__ __launch_bounds__(256) void prep_kernel(const float* __restrict__ W,
                                                   const float* __restrict__ bias,
                                                   __bf16* __restrict__ Wb,
                                                   float* __restrict__ scal) {
  int b = blockIdx.x;
  if (b < 64) {
    int idx = b * 1024 + threadIdx.x * 4;
    int j = idx >> 8;
    float4 w;
    if (j < 255) w = *(const float4*)(W + idx + 256);
    else w = make_float4(0.f, 0.f, 0.f, 0.f);
    bf16x4 o;
    o[0] = (__bf16)w.x; o[1] = (__bf16)w.y; o[2] = (__bf16)w.z; o[3] = (__bf16)w.w;
    *(bf16x4*)(Wb + idx) = o;
  } else if (threadIdx.x < 64) {
    int l = threadIdx.x;
    float4 bv = *(const float4*)(bias + l * 4);
    float s = bv.x * bv.x + bv.y * bv.y + bv.z * bv.z + bv.w * bv.w;
    if (l == 0) s -= bv.x * bv.x;
    for (int m = 1; m < 64; m <<= 1) s += __shfl_xor(s, m);
    if (l == 0) {
      float nb = sqrtf(s);
      float normu = fminf(nb, 1000.0f);
      float th = fmaxf(normu, MINV);
      scal[0] = coshf(th);          // c1
      scal[1] = sinhf(th) / th;     // s1
      scal[2] = s;                  // ||b1||^2
    }
  }
}

// ---- main fused kernel: 64 rows/block, 16 rows/wave ----
__global__ __launch_bounds__(256) void hnn_kernel(const float* __restrict__ h,
                                                  const __bf16* __restrict__ Wb,
                                                  const float* __restrict__ bias,
                                                  const float* __restrict__ gamma,
                                                  const float* __restrict__ beta,
                                                  const float* __restrict__ scal,
                                                  float* __restrict__ out) {
  __shared__ __bf16 Xs[64][264];            // +8 pad
  __shared__ __align__(16) float gs[256];   // gs[0]=0, gs[c]=gamma[c-1]
  __shared__ __align__(16) float bs[256];

  const int tid = threadIdx.x;
  const int wave = tid >> 6;
  const int lane = tid & 63;
  const int lane16 = lane & 15;
  const int quad = lane >> 4;
  const int rowBlock = blockIdx.x * 64;

  if (tid < 255) { gs[tid + 1] = gamma[tid]; bs[tid + 1] = beta[tid]; }
  else if (tid == 255) { gs[0] = 0.f; bs[0] = 0.f; }
  __syncthreads();

  // ---------- Phase A: 4 rows in parallel per iteration (16 lanes/row) ----------
#pragma unroll
  for (int it = 0; it < 4; ++it) {
    const int lrow = wave * 16 + it * 4 + quad;
    const int row = rowBlock + lrow;
    const float4* hp = (const float4*)(h + row * 256 + lane16 * 16);
    float4 hv0 = hp[0], hv1 = hp[1], hv2 = hp[2], hv3 = hp[3];
    float vals[16] = {hv0.x, hv0.y, hv0.z, hv0.w, hv1.x, hv1.y, hv1.z, hv1.w,
                      hv2.x, hv2.y, hv2.z, hv2.w, hv3.x, hv3.y, hv3.z, hv3.w};
    float s1l = 0.f, s2l = 0.f;
#pragma unroll
    for (int i = 0; i < 16; ++i) { s1l += vals[i]; s2l += vals[i] * vals[i]; }
    if (lane16 == 0) { s1l -= vals[0]; s2l -= vals[0] * vals[0]; }
#pragma unroll
    for (int m = 1; m < 16; m <<= 1) {
      s1l += __shfl_xor(s1l, m);
      s2l += __shfl_xor(s2l, m);
    }
    float h0 = __shfl(vals[0], lane & 48);   // group base lane holds h[row][0]
    float yn = fmaxf(sqrtf(s2l), MINV);
    float xc = fmaxf(h0, 1.0f + 1e-7f);
    float theta = acoshf(xc);
    float s = theta / yn;                    // t[k] = s*y[k]
    float mu = s * s1l * (1.0f / 255.0f);
    float var = s * s * (s2l * (1.0f / 255.0f)) - mu * mu;
    float rstd = rsqrtf(var + 1e-5f);
    float a = s * rstd;
    float bshift = -mu * rstd;
    const float4* gp = (const float4*)(gs + lane16 * 16);
    const float4* bp = (const float4*)(bs + lane16 * 16);
    bf16x8 o0, o1;
#pragma unroll
    for (int q = 0; q < 4; ++q) {
      float4 gv = gp[q];
      float4 bv = bp[q];
      float t0 = (a * vals[q * 4 + 0] + bshift) * gv.x + bv.x;
      float t1 = (a * vals[q * 4 + 1] + bshift) * gv.y + bv.y;
      float t2 = (a * vals[q * 4 + 2] + bshift) * gv.z + bv.z;
      float t3 = (a * vals[q * 4 + 3] + bshift) * gv.w + bv.w;
      if (q < 2) {
        o0[q * 4 + 0] = (__bf16)t0; o0[q * 4 + 1] = (__bf16)t1;
        o0[q * 4 + 2] = (__bf16)t2; o0[q * 4 + 3] = (__bf16)t3;
      } else {
        o1[(q - 2) * 4 + 0] = (__bf16)t0; o1[(q - 2) * 4 + 1] = (__bf16)t1;
        o1[(q - 2) * 4 + 2] = (__bf16)t2; o1[(q - 2) * 4 + 3] = (__bf16)t3;
      }
    }
    *(bf16x8*)(&Xs[lrow][lane16 * 16]) = o0;
    *(bf16x8*)(&Xs[lrow][lane16 * 16 + 8]) = o1;
  }
  __syncthreads();

  // ---------- Phase B: v = tn @ Wb^T (16 rows x 256 cols per wave) ----------
  floatx4 acc[16];
#pragma unroll
  for (int jt = 0; jt < 16; ++jt) acc[jt] = (floatx4){0.f, 0.f, 0.f, 0.f};

  const __bf16* wbase = Wb + lane16 * 256 + quad * 8;
  const __bf16* xrow = &Xs[wave * 16 + lane16][quad * 8];

#pragma unroll
  for (int kk = 0; kk < 8; ++kk) {
    bf16x8 afr = *(const bf16x8*)(xrow + kk * 32);
#pragma unroll
    for (int jt = 0; jt < 16; ++jt) {
      bf16x8 bfr = *(const bf16x8*)(wbase + jt * 4096 + kk * 32);
      acc[jt] = __builtin_amdgcn_mfma_f32_16x16x32_bf16(afr, bfr, acc[jt], 0, 0, 0);
    }
  }

  // ---------- Phase C: hyperbolic epilogue ----------
  const float c1 = scal[0];
  const float s1s = scal[1];
  const float tb2 = scal[2];

  float bb1[16];
#pragma unroll
  for (int jt = 0; jt < 16; ++jt) {
    int j = jt * 16 + lane16;
    bb1[jt] = (j < 255) ? bias[j + 1] : 0.f;
  }

#pragma unroll
  for (int e = 0; e < 4; ++e) {
    float* orow = out + (rowBlock + wave * 16 + quad * 4 + e) * 256;
    float sv2 = 0.f, svb = 0.f;
#pragma unroll
    for (int jt = 0; jt < 16; ++jt) {
      float v = acc[jt][e];
      sv2 += v * v;
      svb += v * bb1[jt];
    }
#pragma unroll
    for (int m = 1; m < 16; m <<= 1) {
      sv2 += __shfl_xor(sv2, m);
      svb += __shfl_xor(svb, m);
    }
    float n = fmaxf(sqrtf(sv2), MINV);
    float inv_n = 1.0f / n;
    float alpha = svb * inv_n;
    float ex = __expf(n);
    float iex = 1.0f / ex;
    float ch = 0.5f * (ex + iex), sh = 0.5f * (ex - iex);
    float beta_ = c1 * sh + s1s * alpha * (ch - 1.0f);
    float rn2 = beta_ * beta_ + 2.0f * beta_ * s1s * alpha + s1s * s1s * tb2;
    float rn = sqrtf(fmaxf(rn2, 0.f));
    float res0 = sqrtf(1.0f + rn2);
    float th3 = __logf(res0 + rn);             // acosh(sqrt(1+rn2)) == log(res0+rn)
    float sc3 = th3 / fmaxf(rn, MINV);
    float cvn = beta_ * inv_n;

    float sx2 = 0.f;
#pragma unroll
    for (int jt = 0; jt < 16; ++jt) {
      float x = fmaxf(sc3 * (cvn * acc[jt][e] + s1s * bb1[jt]), 0.f);
      sx2 += x * x;
    }
#pragma unroll
    for (int m = 1; m < 16; m <<= 1) sx2 += __shfl_xor(sx2, m);
    float n2 = fmaxf(sqrtf(sx2), MINV);
    float e2 = __expf(n2);
    float ie2 = 1.0f / e2;
    float scl = 0.5f * (e2 - ie2) / n2;        // sinh(n2)/n2

#pragma unroll
    for (int jt = 0; jt < 16; ++jt) {
      float x = fmaxf(sc3 * (cvn * acc[jt][e] + s1s * bb1[jt]), 0.f);
      int j = jt * 16 + lane16;
      if (j < 255) orow[j + 1] = scl * x;
    }
    if (lane16 == 0) orow[0] = 0.5f * (e2 + ie2);
  }
}

extern "C" void kernel_launch(void* const* d_in, const int* in_sizes, int n_in,
                              void* d_out, int out_size, void* d_ws, size_t ws_size,
                              hipStream_t stream) {
  const float* h     = (const float*)d_in[0];
  const float* W     = (const float*)d_in[1];
  const float* bias  = (const float*)d_in[2];
  const float* gamma = (const float*)d_in[3];
  const float* beta  = (const float*)d_in[4];
  float* out = (float*)d_out;

  __bf16* Wb  = (__bf16*)d_ws;                   // 128 KiB
  float* scal = (float*)((char*)d_ws + 131072);  // 3 floats

  prep_kernel<<<dim3(65), dim3(256), 0, stream>>>(W, bias, Wb, scal);
  hnn_kernel<<<dim3(4096), dim3(256), 0, stream>>>(h, Wb, bias, gamma, beta, scal, out);
}